// Round 2
// baseline (1446.530 us; speedup 1.0000x reference)
//
#include <hip/hip_runtime.h>

#define BB 8
#define NN 2048
#define KNN 20
#define NPOS (BB*NN)          // 16384 points
#define NEDGE (NPOS*KNN)      // 327680 edge positions

// ---------- f16 helpers ----------
union H16 { _Float16 h; unsigned short u; };
__device__ __forceinline__ unsigned short f2h(float f){ H16 x; x.h = (_Float16)f; return x.u; }
__device__ __forceinline__ float h2f(unsigned short u){ H16 x; x.u = u; return (float)x.h; }
// monotone map f32 -> u32 (order-preserving), and inverse
__device__ __forceinline__ unsigned fmap(float f){ unsigned u = __float_as_uint(f); return (u & 0x80000000u) ? ~u : (u | 0x80000000u); }
__device__ __forceinline__ float funmap(unsigned m){ return __uint_as_float((m & 0x80000000u) ? (m & 0x7fffffffu) : ~m); }

// ---------- 1. de-mean: xt layout [b][n][4] (xyz + pad) ----------
__global__ __launch_bounds__(256) void k_demean(const float* __restrict__ pts, float* __restrict__ xt){
  int b = blockIdx.x / 3, d = blockIdx.x % 3;
  const float* row = pts + (size_t)(b*3 + d)*NN;
  __shared__ float red[256];
  int t = threadIdx.x;
  float s = 0.f;
  for (int n = t; n < NN; n += 256) s += row[n];
  red[t] = s; __syncthreads();
  for (int w = 128; w > 0; w >>= 1){ if (t < w) red[t] += red[t+w]; __syncthreads(); }
  float mean = red[0] * (1.0f/NN);
  for (int n = t; n < NN; n += 256) xt[(size_t)(b*NN + n)*4 + d] = row[n] - mean;
}

// ---------- 2. knn: top-20 by neg_dist; neighbor ORDER irrelevant downstream ----------
__global__ __launch_bounds__(256) void k_knn(const float* __restrict__ xt, int* __restrict__ idx){
  __shared__ float4 xl[NN];                 // 32 KB
  __shared__ float tv[KNN][256];            // 20 KB
  __shared__ unsigned short ti[KNN][256];   // 10 KB
  int b = blockIdx.x >> 3, chunk = blockIdx.x & 7;
  int t = threadIdx.x;
  const float4* xb = (const float4*)xt + (size_t)b*NN;
  for (int m = t; m < NN; m += 256){
    float4 v = xb[m];
    v.w = v.x*v.x + v.y*v.y + v.z*v.z;
    xl[m] = v;
  }
  __syncthreads();
  int n = (chunk << 8) + t;
  float4 xn = xl[n];
  float sqn = xn.w;
  float curmin = 1e30f; int minslot = 0;
  for (int m = 0; m < KNN; ++m){
    float4 xm = xl[m];
    float nd = 2.f*(xn.x*xm.x + xn.y*xm.y + xn.z*xm.z) - sqn - xm.w;
    tv[m][t] = nd; ti[m][t] = (unsigned short)m;
    if (nd < curmin){ curmin = nd; minslot = m; }
  }
  for (int m = KNN; m < NN; ++m){
    float4 xm = xl[m];
    float nd = 2.f*(xn.x*xm.x + xn.y*xm.y + xn.z*xm.z) - sqn - xm.w;
    if (nd > curmin){
      tv[minslot][t] = nd; ti[minslot][t] = (unsigned short)m;
      curmin = tv[0][t]; minslot = 0;
      #pragma unroll
      for (int j = 1; j < KNN; ++j){ float v = tv[j][t]; if (v < curmin){ curmin = v; minslot = j; } }
    }
  }
  int* op = idx + (size_t)(b*NN + n)*KNN;
  #pragma unroll
  for (int j = 0; j < KNN; ++j) op[j] = (int)ti[j][t];
}

// ---------- 3. conv1: gather (nbr xyz, ctr xyz) -> y1 = W1*h, raw f16 ----------
__global__ __launch_bounds__(256) void k_conv1(const float* __restrict__ xt, const int* __restrict__ idx,
    const float* __restrict__ W1, unsigned short* __restrict__ y1){
  __shared__ float Wl[64*6];
  int t = threadIdx.x;
  for (int i = t; i < 384; i += 256) Wl[i] = W1[i];
  __syncthreads();
  int e = blockIdx.x*256 + t;
  int p = e / KNN;
  int b = p >> 11, n = p & (NN-1);
  int nb = idx[e];
  const float4* xb = (const float4*)xt + (size_t)b*NN;
  float4 xnb = xb[nb], xcn = xb[n];
  unsigned short* yo = y1 + (size_t)e*64;
  #pragma unroll
  for (int o = 0; o < 64; o += 8){
    unsigned short pk[8];
    #pragma unroll
    for (int q = 0; q < 8; ++q){
      const float* w = &Wl[(o+q)*6];
      float v = w[0]*xnb.x + w[1]*xnb.y + w[2]*xnb.z + w[3]*xcn.x + w[4]*xcn.y + w[5]*xcn.z;
      pk[q] = f2h(v);
    }
    uint4 u;
    u.x = (unsigned int)pk[0] | ((unsigned int)pk[1]<<16);
    u.y = (unsigned int)pk[2] | ((unsigned int)pk[3]<<16);
    u.z = (unsigned int)pk[4] | ((unsigned int)pk[5]<<16);
    u.w = (unsigned int)pk[6] | ((unsigned int)pk[7]<<16);
    *reinterpret_cast<uint4*>(yo + o) = u;
  }
}

// ---------- 4. stats for y1 (C=64, f16), 64-sharded sums ----------
__global__ __launch_bounds__(256) void k_stats1(const unsigned short* __restrict__ y, float* __restrict__ st){
  int t = threadIdx.x;
  int c = t & 63, ro = t >> 6;   // 4 rows per iteration
  float s = 0.f, q = 0.f;
  int nrb = NEDGE/4;
  for (int rb = blockIdx.x; rb < nrb; rb += gridDim.x){
    int r = rb*4 + ro;
    float v = h2f(y[(size_t)r*64 + c]);
    s += v; q += v*v;
  }
  __shared__ float red[256];
  red[t] = s; __syncthreads();
  if (t < 64){ for (int g = 1; g < 4; ++g) s += red[t + g*64]; }
  __syncthreads(); red[t] = q; __syncthreads();
  if (t < 64){
    for (int g = 1; g < 4; ++g) q += red[t + g*64];
    int shard = blockIdx.x & 63;
    atomicAdd(&st[c*64 + shard], s);
    atomicAdd(&st[4096 + c*64 + shard], q);
  }
}

// ---------- 5. finalize BN from sharded stats ----------
__global__ void k_fin(const float* __restrict__ st, const float* __restrict__ gw, const float* __restrict__ bw,
                      float* __restrict__ act, int C, float inv_n){
  int c = threadIdx.x;
  if (c >= C) return;
  float s = 0.f, q = 0.f;
  for (int i = 0; i < 64; ++i){ s += st[c*64 + i]; q += st[(size_t)C*64 + c*64 + i]; }
  float mean = s*inv_n;
  float var = q*inv_n - mean*mean;
  float sc = gw[c] * rsqrtf(var + 1e-5f);
  act[c] = sc; act[C + c] = bw[c] - mean*sc;
}

// ---------- 6. tiled conv with fused input-pool / stats / output-minmax ----------
// 64 positions x 64 out-channels per block, 256 threads, 4x4 acc per thread.
// OUTMODE: 0 = write f16, 1 = write f32, 2 = no write, pool raw min/max over k (layer 4).
// POOLCOFF >= 0: pool the post-act INPUT A-tile over k into xc[:, POOLCOFF + cin] (uint-max, values>=0).
template<int CIN, int COUT, bool ACT, bool INF16, int OUTMODE, int POOLCOFF>
__global__ __launch_bounds__(256) void k_conv(const void* __restrict__ in_, const float* __restrict__ W,
    const float* __restrict__ actp, void* __restrict__ out_, float* __restrict__ stat,
    unsigned int* __restrict__ xcU, unsigned int* __restrict__ mxb, unsigned int* __restrict__ mnb){
  __shared__ float AB[64][68];            // rows 0-31: A [k][pos]; rows 32-63: B [k][och]
  __shared__ float scl[ACT ? CIN : 1];
  __shared__ float shf[ACT ? CIN : 1];
  int t = threadIdx.x;
  if constexpr (ACT){
    for (int i = t; i < CIN; i += 256){ scl[i] = actp[i]; shf[i] = actp[CIN + i]; }
  }
  __syncthreads();
  int tx = t & 15, ty = t >> 4;
  int p0 = blockIdx.x * 64;
  int o0 = blockIdx.y * 64;
  float acc[4][4] = {};
  for (int k0 = 0; k0 < CIN; k0 += 32){
    if constexpr (INF16){
      const unsigned short* in = (const unsigned short*)in_;
      int pr = t >> 2, kc = (t & 3) << 3;
      uint4 raw = *reinterpret_cast<const uint4*>(in + (size_t)(p0 + pr)*CIN + k0 + kc);
      unsigned w4[4] = {raw.x, raw.y, raw.z, raw.w};
      #pragma unroll
      for (int q = 0; q < 4; ++q){
        int kk = kc + 2*q;
        float va = h2f((unsigned short)(w4[q] & 0xffffu));
        float vb = h2f((unsigned short)(w4[q] >> 16));
        if constexpr (ACT){
          va = fmaxf(0.f, scl[k0+kk]*va + shf[k0+kk]);
          vb = fmaxf(0.f, scl[k0+kk+1]*vb + shf[k0+kk+1]);
        }
        AB[kk][pr] = va; AB[kk+1][pr] = vb;
      }
    } else {
      const float* in = (const float*)in_;
      int pr = t >> 3, kc = (t & 7) << 2;
      #pragma unroll
      for (int pass = 0; pass < 2; ++pass){
        int pp = pr + (pass << 5);
        float4 a4 = *reinterpret_cast<const float4*>(in + (size_t)(p0 + pp)*CIN + k0 + kc);
        if constexpr (ACT){
          a4.x = fmaxf(0.f, scl[k0+kc+0]*a4.x + shf[k0+kc+0]);
          a4.y = fmaxf(0.f, scl[k0+kc+1]*a4.y + shf[k0+kc+1]);
          a4.z = fmaxf(0.f, scl[k0+kc+2]*a4.z + shf[k0+kc+2]);
          a4.w = fmaxf(0.f, scl[k0+kc+3]*a4.w + shf[k0+kc+3]);
        }
        AB[kc+0][pp] = a4.x; AB[kc+1][pp] = a4.y; AB[kc+2][pp] = a4.z; AB[kc+3][pp] = a4.w;
      }
    }
    {
      int orow = t >> 3, kc = (t & 7) << 2;
      #pragma unroll
      for (int pass = 0; pass < 2; ++pass){
        int oo = orow + (pass << 5);
        float4 w4 = *reinterpret_cast<const float4*>(W + (size_t)(o0 + oo)*CIN + k0 + kc);
        AB[32+kc+0][oo] = w4.x; AB[32+kc+1][oo] = w4.y; AB[32+kc+2][oo] = w4.z; AB[32+kc+3][oo] = w4.w;
      }
    }
    __syncthreads();
    if constexpr (POOLCOFF >= 0){
      // pool post-act input over k within this block (block spans <= 4 points: gcd(64,20)=4)
      if (blockIdx.y == 0 && t < 128){
        int kk = t & 31, pslot = t >> 5;
        int q0 = p0 / KNN;
        int qq = q0 + pslot;
        if (qq * KNN < p0 + 64){
          int lo = max(qq*KNN, p0), hi = min(qq*KNN + KNN, p0 + 64);
          float m = 0.f;   // post-relu values are >= 0
          for (int e = lo; e < hi; ++e) m = fmaxf(m, AB[kk][e - p0]);
          atomicMax(&xcU[(size_t)qq*512 + POOLCOFF + k0 + kk], __float_as_uint(m));
        }
      }
    }
    #pragma unroll
    for (int k = 0; k < 32; ++k){
      float4 a4 = *reinterpret_cast<const float4*>(&AB[k][tx << 2]);
      float4 b4 = *reinterpret_cast<const float4*>(&AB[32 + k][ty << 2]);
      acc[0][0] += b4.x*a4.x; acc[0][1] += b4.x*a4.y; acc[0][2] += b4.x*a4.z; acc[0][3] += b4.x*a4.w;
      acc[1][0] += b4.y*a4.x; acc[1][1] += b4.y*a4.y; acc[1][2] += b4.y*a4.z; acc[1][3] += b4.y*a4.w;
      acc[2][0] += b4.z*a4.x; acc[2][1] += b4.z*a4.y; acc[2][2] += b4.z*a4.z; acc[2][3] += b4.z*a4.w;
      acc[3][0] += b4.w*a4.x; acc[3][1] += b4.w*a4.y; acc[3][2] += b4.w*a4.z; acc[3][3] += b4.w*a4.w;
    }
    __syncthreads();
  }
  int prow = p0 + (tx << 2), oc = o0 + (ty << 2);
  if constexpr (OUTMODE == 0){
    unsigned short* out = (unsigned short*)out_;
    #pragma unroll
    for (int i = 0; i < 4; ++i){
      ushort4 u;
      u.x = f2h(acc[0][i]); u.y = f2h(acc[1][i]); u.z = f2h(acc[2][i]); u.w = f2h(acc[3][i]);
      *reinterpret_cast<ushort4*>(out + (size_t)(prow+i)*COUT + oc) = u;
    }
  } else if constexpr (OUTMODE == 1){
    float* out = (float*)out_;
    #pragma unroll
    for (int i = 0; i < 4; ++i){
      float4 u; u.x = acc[0][i]; u.y = acc[1][i]; u.z = acc[2][i]; u.w = acc[3][i];
      *reinterpret_cast<float4*>(out + (size_t)(prow+i)*COUT + oc) = u;
    }
  } else {
    // raw min/max over k for layer-4 output (BN applied later in k_pool4)
    #pragma unroll
    for (int j = 0; j < 4; ++j)
      #pragma unroll
      for (int i = 0; i < 4; ++i)
        AB[(tx<<2)+i][(ty<<2)+j] = acc[j][i];
    __syncthreads();
    {
      int chL = t & 63, pslot = t >> 6;
      int q0 = p0 / KNN, qq = q0 + pslot;
      if (qq * KNN < p0 + 64){
        int lo = max(qq*KNN, p0), hi = min(qq*KNN + KNN, p0 + 64);
        float mx = -1e30f, mn = 1e30f;
        for (int e = lo; e < hi; ++e){ float v = AB[e - p0][chL]; mx = fmaxf(mx, v); mn = fminf(mn, v); }
        atomicMax(&mxb[(size_t)qq*COUT + o0 + chL], fmap(mx));
        atomicMin(&mnb[(size_t)qq*COUT + o0 + chL], fmap(mn));
      }
    }
    __syncthreads();
  }
  // fused per-channel sum/sumsq (64-sharded)
  {
    float* f = &AB[0][0];
    float s[4], qs[4];
    #pragma unroll
    for (int j = 0; j < 4; ++j){
      s[j]  = acc[j][0] + acc[j][1] + acc[j][2] + acc[j][3];
      qs[j] = acc[j][0]*acc[j][0] + acc[j][1]*acc[j][1] + acc[j][2]*acc[j][2] + acc[j][3]*acc[j][3];
    }
    #pragma unroll
    for (int j = 0; j < 4; ++j){
      f[((ty<<2)+j)*16 + tx] = s[j];
      f[1024 + ((ty<<2)+j)*16 + tx] = qs[j];
    }
    __syncthreads();
    if (t < 64){
      float ss = 0.f, qq2 = 0.f;
      #pragma unroll
      for (int i = 0; i < 16; ++i){ ss += f[t*16 + i]; qq2 += f[1024 + t*16 + i]; }
      int shard = blockIdx.x & 63;
      atomicAdd(&stat[(size_t)(o0 + t)*64 + shard], ss);
      atomicAdd(&stat[(size_t)COUT*64 + (size_t)(o0 + t)*64 + shard], qq2);
    }
  }
}

// ---------- 7. layer-4 pool finalize: pick max or min by sign of scale, BN+ReLU ----------
__global__ __launch_bounds__(256) void k_pool4(const unsigned int* __restrict__ mx, const unsigned int* __restrict__ mn,
    const float* __restrict__ ac4, float* __restrict__ xc){
  int g = blockIdx.x*256 + threadIdx.x;
  int p = g >> 8, c = g & 255;
  float sc = ac4[c], sh = ac4[256 + c];
  float raw = (sc >= 0.f) ? funmap(mx[g]) : funmap(mn[g]);
  xc[(size_t)p*512 + 256 + c] = fmaxf(0.f, sc*raw + sh);
}

// ---------- 8. final: bn5+relu on y5 [p][512] -> out [b][512][n] ----------
__global__ void k_out(const float* __restrict__ y5, const float* __restrict__ act, float* __restrict__ out){
  __shared__ float tile[32][33];
  int b = blockIdx.z; int n0 = blockIdx.x*32; int c0 = blockIdx.y*32;
  int lx = threadIdx.x, ly = threadIdx.y;
  float sc = act[c0 + lx], sh = act[512 + c0 + lx];
  for (int yy = ly; yy < 32; yy += 8){
    float v = y5[((size_t)(b*NN + n0 + yy))*512 + c0 + lx];
    tile[yy][lx] = fmaxf(0.f, sc*v + sh);
  }
  __syncthreads();
  for (int yy = ly; yy < 32; yy += 8){
    out[((size_t)(b*512 + c0 + yy))*NN + n0 + lx] = tile[lx][yy];
  }
}

// ---------- launch ----------
extern "C" void kernel_launch(void* const* d_in, const int* in_sizes, int n_in,
                              void* d_out, int out_size, void* d_ws, size_t ws_size,
                              hipStream_t stream){
  const float* pts = (const float*)d_in[0];
  const float* W1 = (const float*)d_in[1];
  const float* W2 = (const float*)d_in[2];
  const float* W3 = (const float*)d_in[3];
  const float* W4 = (const float*)d_in[4];
  const float* W5 = (const float*)d_in[5];
  const float* g1 = (const float*)d_in[6];  const float* b1 = (const float*)d_in[7];
  const float* g2 = (const float*)d_in[8];  const float* b2 = (const float*)d_in[9];
  const float* g3 = (const float*)d_in[10]; const float* b3 = (const float*)d_in[11];
  const float* g4 = (const float*)d_in[12]; const float* b4 = (const float*)d_in[13];
  const float* g5 = (const float*)d_in[14]; const float* b5 = (const float*)d_in[15];

  char* ws = (char*)d_ws;
  // layout (peak 156 MiB):
  float*          xt    = (float*)(ws + 0);              //   256 KB
  int*            idx   = (int*)  (ws + 262144);         //  1.25 MB
  float*          stats = (float*)(ws + 1572864);        //   512 KB (sharded sums, all layers)
  float*          acts  = (float*)(ws + 2097152);        //     8 KB
  unsigned short* y2    = (unsigned short*)(ws + 4194304);   // 40 MiB
  unsigned int*   mx    = (unsigned int*)(ws + 4194304);     // 16 MiB (overlays dead y2)
  unsigned int*   mn    = (unsigned int*)(ws + 20971520);    // 16 MiB
  unsigned short* y1    = (unsigned short*)(ws + 46137344);  // 40 MiB
  unsigned short* y3    = (unsigned short*)(ws + 46137344);  // 80 MiB (overlays dead y1)
  float*          y5    = (float*)(ws + 46137344);           // 32 MiB (overlays dead y3)
  float*          xc    = (float*)(ws + 130023424);          // 32 MiB
  unsigned int*   xcU   = (unsigned int*)xc;
  float* out = (float*)d_out;

  float* st1 = stats + 0,   *st2 = stats + 8192, *st3 = stats + 16384, *st4 = stats + 32768, *st5 = stats + 65536;
  float* ac1 = acts + 0,    *ac2 = acts + 128,   *ac3 = acts + 256,    *ac4 = acts + 512,    *ac5 = acts + 1024;

  hipMemsetAsync(stats, 0, 524288, stream);
  hipMemsetAsync(xc, 0, 33554432, stream);                 // atomic-max init (values >= 0)
  k_demean<<<24, 256, 0, stream>>>(pts, xt);
  k_knn<<<64, 256, 0, stream>>>(xt, idx);
  k_conv1<<<NEDGE/256, 256, 0, stream>>>(xt, idx, W1, y1);
  k_stats1<<<256, 256, 0, stream>>>(y1, st1);
  k_fin<<<1, 64, 0, stream>>>(st1, g1, b1, ac1, 64, 1.f/NEDGE);
  k_conv<64,64,true,true,0,0><<<dim3(NEDGE/64,1), 256, 0, stream>>>(y1, W2, ac1, y2, st2, xcU, nullptr, nullptr);
  k_fin<<<1, 64, 0, stream>>>(st2, g2, b2, ac2, 64, 1.f/NEDGE);
  k_conv<64,128,true,true,0,64><<<dim3(NEDGE/64,2), 256, 0, stream>>>(y2, W3, ac2, y3, st3, xcU, nullptr, nullptr);
  k_fin<<<1, 128, 0, stream>>>(st3, g3, b3, ac3, 128, 1.f/NEDGE);
  hipMemsetAsync(mx, 0x00, 16777216, stream);              // mapped -inf
  hipMemsetAsync(mn, 0xFF, 16777216, stream);              // mapped +inf
  k_conv<128,256,true,true,2,128><<<dim3(NEDGE/64,4), 256, 0, stream>>>(y3, W4, ac3, nullptr, st4, xcU, mx, mn);
  k_fin<<<1, 256, 0, stream>>>(st4, g4, b4, ac4, 256, 1.f/NEDGE);
  k_pool4<<<NPOS*256/256, 256, 0, stream>>>(mx, mn, ac4, xc);
  k_conv<512,512,false,false,1,-1><<<dim3(NPOS/64,8), 256, 0, stream>>>(xc, W5, nullptr, y5, st5, nullptr, nullptr, nullptr);
  k_fin<<<1, 512, 0, stream>>>(st5, g5, b5, ac5, 512, 1.f/NPOS);
  k_out<<<dim3(NN/32, 16, BB), dim3(32, 8), 0, stream>>>(y5, ac5, out);
}

// Round 3
// 662.007 us; speedup vs baseline: 2.1851x; 2.1851x over previous
//
#include <hip/hip_runtime.h>

#define BB 8
#define NN 2048
#define KNN 20
#define NPOS (BB*NN)          // 16384 points
#define NEDGE (NPOS*KNN)      // 327680 edge positions

typedef _Float16 f16x8 __attribute__((ext_vector_type(8)));
typedef float f32x4 __attribute__((ext_vector_type(4)));

union H16 { _Float16 h; unsigned short u; };
__device__ __forceinline__ unsigned short f2h(float f){ H16 x; x.h = (_Float16)f; return x.u; }
__device__ __forceinline__ float h2f(unsigned short u){ H16 x; x.u = u; return (float)x.h; }
__device__ __forceinline__ unsigned fmap(float f){ unsigned u = __float_as_uint(f); return (u & 0x80000000u) ? ~u : (u | 0x80000000u); }
__device__ __forceinline__ float funmap(unsigned m){ return __uint_as_float((m & 0x80000000u) ? (m & 0x7fffffffu) : ~m); }

// ---------- 1. de-mean: xt layout [b][n][4] (xyz + |x|^2 slot filled later in knn) ----------
__global__ __launch_bounds__(256) void k_demean(const float* __restrict__ pts, float* __restrict__ xt){
  int b = blockIdx.x / 3, d = blockIdx.x % 3;
  const float* row = pts + (size_t)(b*3 + d)*NN;
  __shared__ float red[256];
  int t = threadIdx.x;
  float s = 0.f;
  for (int n = t; n < NN; n += 256) s += row[n];
  red[t] = s; __syncthreads();
  for (int w = 128; w > 0; w >>= 1){ if (t < w) red[t] += red[t+w]; __syncthreads(); }
  float mean = red[0] * (1.0f/NN);
  for (int n = t; n < NN; n += 256) xt[(size_t)(b*NN + n)*4 + d] = row[n] - mean;
}

// ---------- 2. knn: 512 blocks, 32 points/block, 8 threads/point ----------
__global__ __launch_bounds__(256) void k_knn(const float* __restrict__ xt, unsigned short* __restrict__ idxo){
  __shared__ float4 xl[NN];                 // 32 KB
  __shared__ float tv[KNN][256];            // 20 KB
  __shared__ unsigned short ti[KNN][256];   // 10 KB
  int b = blockIdx.x >> 6;                  // 64 blocks per batch
  int pbase = (blockIdx.x & 63) * 32;
  int t = threadIdx.x;
  const float4* xb = (const float4*)xt + (size_t)b*NN;
  for (int m = t; m < NN; m += 256){
    float4 v = xb[m];
    v.w = v.x*v.x + v.y*v.y + v.z*v.z;
    xl[m] = v;
  }
  __syncthreads();
  int pl = t >> 3, g = t & 7;
  int n = pbase + pl;
  float4 xn = xl[n];
  float sqn = xn.w;
  // fill first 20 of this thread's chunk (m = g + 8j, conflict-free / broadcast)
  for (int j = 0; j < 20; ++j){
    int m = g + (j << 3);
    float4 xm = xl[m];
    float nd = 2.f*(xn.x*xm.x + xn.y*xm.y + xn.z*xm.z) - sqn - xm.w;
    tv[j][t] = nd; ti[j][t] = (unsigned short)m;
  }
  float curmin = tv[0][t]; int minslot = 0;
  #pragma unroll
  for (int j = 1; j < 20; ++j){ float v = tv[j][t]; if (v < curmin){ curmin = v; minslot = j; } }
  for (int j = 20; j < 256; ++j){
    int m = g + (j << 3);
    float4 xm = xl[m];
    float nd = 2.f*(xn.x*xm.x + xn.y*xm.y + xn.z*xm.z) - sqn - xm.w;
    if (nd > curmin){
      tv[minslot][t] = nd; ti[minslot][t] = (unsigned short)m;
      curmin = tv[0][t]; minslot = 0;
      #pragma unroll
      for (int u = 1; u < 20; ++u){ float vv = tv[u][t]; if (vv < curmin){ curmin = vv; minslot = u; } }
    }
  }
  __syncthreads();
  // tree-merge 8 partial lists -> column g=0
  for (int s = 4; s; s >>= 1){
    if (g < s){
      int src = t + s;
      for (int jj = 0; jj < 20; ++jj){
        float v = tv[jj][src];
        if (v > curmin){
          unsigned short mi = ti[jj][src];
          tv[minslot][t] = v; ti[minslot][t] = mi;
          curmin = tv[0][t]; minslot = 0;
          #pragma unroll
          for (int u = 1; u < 20; ++u){ float vv = tv[u][t]; if (vv < curmin){ curmin = vv; minslot = u; } }
        }
      }
    }
    __syncthreads();
  }
  if (g == 0){
    unsigned short* op = idxo + (size_t)(b*NN + pbase + pl)*KNN;
    #pragma unroll
    for (int j = 0; j < 20; ++j) op[j] = ti[j][t];
  }
}

// ---------- 3. conv1: gather (nbr xyz, ctr xyz) -> y1 = W1*h, raw f16 [NEDGE][64] ----------
__global__ __launch_bounds__(256) void k_conv1(const float* __restrict__ xt, const unsigned short* __restrict__ idx,
    const float* __restrict__ W1, unsigned short* __restrict__ y1){
  __shared__ float Wl[64*6];
  int t = threadIdx.x;
  for (int i = t; i < 384; i += 256) Wl[i] = W1[i];
  __syncthreads();
  int e = blockIdx.x*256 + t;
  int p = e / KNN;
  int b = p >> 11;
  int n = p & (NN-1);
  int nb = idx[e];
  const float4* xb = (const float4*)xt + (size_t)b*NN;
  float4 xnb = xb[nb], xcn = xb[n];
  unsigned short* yo = y1 + (size_t)e*64;
  #pragma unroll
  for (int o = 0; o < 64; o += 8){
    unsigned short pk[8];
    #pragma unroll
    for (int q = 0; q < 8; ++q){
      const float* w = &Wl[(o+q)*6];
      float v = w[0]*xnb.x + w[1]*xnb.y + w[2]*xnb.z + w[3]*xcn.x + w[4]*xcn.y + w[5]*xcn.z;
      pk[q] = f2h(v);
    }
    uint4 u;
    u.x = (unsigned)pk[0] | ((unsigned)pk[1]<<16);
    u.y = (unsigned)pk[2] | ((unsigned)pk[3]<<16);
    u.z = (unsigned)pk[4] | ((unsigned)pk[5]<<16);
    u.w = (unsigned)pk[6] | ((unsigned)pk[7]<<16);
    *reinterpret_cast<uint4*>(yo + o) = u;
  }
}

// ---------- 4. stats for y1 (C=64 f16), 64-sharded ----------
__global__ __launch_bounds__(256) void k_stats1(const unsigned short* __restrict__ y, float* __restrict__ st){
  int t = threadIdx.x;
  int c = t & 63, ro = t >> 6;
  float s = 0.f, q = 0.f;
  for (int rb = blockIdx.x; rb < NEDGE/4; rb += gridDim.x){
    float v = h2f(y[(size_t)(rb*4 + ro)*64 + c]);
    s += v; q += v*v;
  }
  __shared__ float red[256];
  red[t] = s; __syncthreads();
  if (t < 64){ for (int g = 1; g < 4; ++g) s += red[t + g*64]; }
  __syncthreads(); red[t] = q; __syncthreads();
  if (t < 64){
    for (int g = 1; g < 4; ++g) q += red[t + g*64];
    int shard = blockIdx.x & 63;
    atomicAdd(&st[c*64 + shard], s);
    atomicAdd(&st[64*64 + c*64 + shard], q);
  }
}

// ---------- 5. finalize BN -> interleaved act[2c]=scale, act[2c+1]=shift ----------
__global__ void k_fin(const float* __restrict__ st, const float* __restrict__ gw, const float* __restrict__ bw,
                      float* __restrict__ act, int C, float inv_n){
  int c = threadIdx.x;
  if (c >= C) return;
  float s = 0.f, q = 0.f;
  for (int i = 0; i < 64; ++i){ s += st[c*64 + i]; q += st[(size_t)C*64 + c*64 + i]; }
  float mean = s*inv_n;
  float var = q*inv_n - mean*mean;
  float sc = gw[c] * rsqrtf(var + 1e-5f);
  act[2*c] = sc; act[2*c+1] = bw[c] - mean*sc;
}

// ---------- 6. max-over-k pool of a 64-ch slab: xc[q][xcoff + c] = max_k relu(sc*y+sh), f16 ----------
__global__ __launch_bounds__(256) void k_max64(const unsigned short* __restrict__ y, const float* __restrict__ actp,
    unsigned short* __restrict__ xc, int xcoff){
  int gidx = blockIdx.x*256 + threadIdx.x;
  int q = gidx >> 5, cp = gidx & 31;
  int c = cp*2;
  float sc0 = actp[2*c],   sh0 = actp[2*c+1];
  float sc1 = actp[2*c+2], sh1 = actp[2*c+3];
  const unsigned* base = reinterpret_cast<const unsigned*>(y + (size_t)q*KNN*64 + c);
  float m0 = 0.f, m1 = 0.f;
  #pragma unroll
  for (int j = 0; j < KNN; ++j){
    unsigned v = base[(size_t)j*32];
    m0 = fmaxf(m0, sc0*h2f((unsigned short)(v & 0xffffu)) + sh0);
    m1 = fmaxf(m1, sc1*h2f((unsigned short)(v >> 16)) + sh1);
  }
  unsigned outv = (unsigned)f2h(m0) | ((unsigned)f2h(m1) << 16);
  *reinterpret_cast<unsigned*>(xc + (size_t)q*512 + xcoff + c) = outv;
}

// ---------- 7. MFMA conv: out[p][o] = sum_ci actf16(in[p][ci]) * W[o][ci] ----------
// tile 128 pos x 64 och per block (4 waves); grid-stride over tiles; B in regs (or global for CIN=512).
// swizzled LDS transpose epilogue: fused stats (+ f16 store | min/max-over-k atomics)
__device__ __forceinline__ int tix(int row, int col){ return row*64 + (col ^ ((row & 7) << 2)); }

template<int CIN, int COUT, bool ACT, bool MINMAX, bool BGLOBAL, bool SPLITIN>
__global__ __launch_bounds__(256) void k_mfma(
    const unsigned short* __restrict__ inA, const unsigned short* __restrict__ inB,
    const float* __restrict__ W, const float* __restrict__ actp,
    unsigned short* __restrict__ out, size_t slab_stride,
    float* __restrict__ stat, unsigned* __restrict__ mx, unsigned* __restrict__ mn,
    int ntiles){
  constexpr int NKC = CIN/32;
  __shared__ __align__(16) float T[128*64];
  int t = threadIdx.x, lane = t & 63, w = t >> 6, g = lane >> 4, r16 = lane & 15;
  int o0 = blockIdx.y * 64;
  const f16x8 zf = 0;

  // weights -> register fragments (B[k][och]: och = o0+16n+r16, k = kc*32+8g+j)
  f16x8 breg[BGLOBAL ? 1 : NKC][4];
  if constexpr (!BGLOBAL){
    #pragma unroll
    for (int kc = 0; kc < NKC; ++kc)
      #pragma unroll
      for (int n = 0; n < 4; ++n){
        const float* wp = W + (size_t)(o0 + 16*n + r16)*CIN + kc*32 + g*8;
        float4 w0 = *reinterpret_cast<const float4*>(wp);
        float4 w1 = *reinterpret_cast<const float4*>(wp + 4);
        f16x8 bv;
        bv[0]=(_Float16)w0.x; bv[1]=(_Float16)w0.y; bv[2]=(_Float16)w0.z; bv[3]=(_Float16)w0.w;
        bv[4]=(_Float16)w1.x; bv[5]=(_Float16)w1.y; bv[6]=(_Float16)w1.z; bv[7]=(_Float16)w1.w;
        breg[kc][n] = bv;
      }
  }
  // BN act params (per-lane 8 channels per kc), f16
  f16x8 scl8[ACT ? NKC : 1], shf8[ACT ? NKC : 1];
  if constexpr (ACT){
    #pragma unroll
    for (int kc = 0; kc < NKC; ++kc){
      int ch0 = kc*32 + g*8;
      const float4* apv = reinterpret_cast<const float4*>(actp + 2*ch0);
      float4 q0 = apv[0], q1 = apv[1], q2 = apv[2], q3 = apv[3];
      f16x8 s, h;
      s[0]=(_Float16)q0.x; h[0]=(_Float16)q0.y; s[1]=(_Float16)q0.z; h[1]=(_Float16)q0.w;
      s[2]=(_Float16)q1.x; h[2]=(_Float16)q1.y; s[3]=(_Float16)q1.z; h[3]=(_Float16)q1.w;
      s[4]=(_Float16)q2.x; h[4]=(_Float16)q2.y; s[5]=(_Float16)q2.z; h[5]=(_Float16)q2.w;
      s[6]=(_Float16)q3.x; h[6]=(_Float16)q3.y; s[7]=(_Float16)q3.z; h[7]=(_Float16)q3.w;
      scl8[kc] = s; shf8[kc] = h;
    }
  }
  float sAcc = 0.f, qAcc = 0.f;
  int cst = t & 63, ps = t >> 6;

  for (int tt = blockIdx.x; tt < ntiles; tt += gridDim.x){
    int p0 = tt * 128;
    int prow = p0 + 32*w + r16;
    f32x4 acc[2][4];
    #pragma unroll
    for (int m = 0; m < 2; ++m)
      #pragma unroll
      for (int n = 0; n < 4; ++n) acc[m][n] = 0.f;

    #pragma unroll
    for (int kc = 0; kc < NKC; ++kc){
      f16x8 af[2];
      #pragma unroll
      for (int m = 0; m < 2; ++m){
        const unsigned short* abase; int kloc, stride;
        if constexpr (SPLITIN){ abase = (kc < NKC/2) ? inA : inB; kloc = kc & (NKC/2 - 1); stride = 64; }
        else { abase = inA; kloc = kc; stride = CIN; }
        f16x8 av = *reinterpret_cast<const f16x8*>(abase + (size_t)(prow + 16*m)*stride + kloc*32 + g*8);
        if constexpr (ACT){
          av = av * scl8[kc] + shf8[kc];
          av = __builtin_elementwise_max(av, zf);
        }
        af[m] = av;
      }
      #pragma unroll
      for (int n = 0; n < 4; ++n){
        f16x8 bv;
        if constexpr (BGLOBAL){
          const float* wp = W + (size_t)(o0 + 16*n + r16)*CIN + kc*32 + g*8;
          float4 w0 = *reinterpret_cast<const float4*>(wp);
          float4 w1 = *reinterpret_cast<const float4*>(wp + 4);
          bv[0]=(_Float16)w0.x; bv[1]=(_Float16)w0.y; bv[2]=(_Float16)w0.z; bv[3]=(_Float16)w0.w;
          bv[4]=(_Float16)w1.x; bv[5]=(_Float16)w1.y; bv[6]=(_Float16)w1.z; bv[7]=(_Float16)w1.w;
        } else bv = breg[kc][n];
        acc[0][n] = __builtin_amdgcn_mfma_f32_16x16x32_f16(af[0], bv, acc[0][n], 0, 0, 0);
        acc[1][n] = __builtin_amdgcn_mfma_f32_16x16x32_f16(af[1], bv, acc[1][n], 0, 0, 0);
      }
    }
    // epilogue: swizzled transpose to LDS
    __syncthreads();
    #pragma unroll
    for (int m = 0; m < 2; ++m)
      #pragma unroll
      for (int n = 0; n < 4; ++n)
        #pragma unroll
        for (int r = 0; r < 4; ++r)
          T[tix(32*w + 16*m + 4*g + r, 16*n + r16)] = acc[m][n][r];
    __syncthreads();
    // fused per-channel stats (accumulate in regs across tiles)
    #pragma unroll
    for (int r = 0; r < 32; ++r){
      float v = T[tix(32*ps + r, cst)];
      sAcc += v; qAcc += v*v;
    }
    if constexpr (!MINMAX){
      // coalesced f16 store
      int row = t >> 1, h = t & 1;
      unsigned short* op = out + (size_t)blockIdx.y*slab_stride + ((size_t)p0 + row)*64 + 32*h;
      unsigned pk[16];
      #pragma unroll
      for (int i = 0; i < 8; ++i){
        float4 v = *reinterpret_cast<const float4*>(&T[tix(row, 32*h + 4*i)]);
        pk[2*i]   = (unsigned)f2h(v.x) | ((unsigned)f2h(v.y) << 16);
        pk[2*i+1] = (unsigned)f2h(v.z) | ((unsigned)f2h(v.w) << 16);
      }
      #pragma unroll
      for (int j = 0; j < 4; ++j){
        uint4 u; u.x = pk[4*j]; u.y = pk[4*j+1]; u.z = pk[4*j+2]; u.w = pk[4*j+3];
        *reinterpret_cast<uint4*>(op + 8*j) = u;
      }
    } else {
      // raw min/max over k-windows (layer 4), atomics to global
      int rlo = p0 + 32*ps, rhi = rlo + 32;
      for (int q = rlo/KNN; q*KNN < rhi; ++q){
        int lo = q*KNN > rlo ? q*KNN : rlo;
        int hi = (q*KNN + KNN) < rhi ? (q*KNN + KNN) : rhi;
        float mxv = -1e30f, mnv = 1e30f;
        for (int r = lo; r < hi; ++r){
          float v = T[tix(r - p0, cst)];
          mxv = fmaxf(mxv, v); mnv = fminf(mnv, v);
        }
        atomicMax(&mx[(size_t)q*COUT + o0 + cst], fmap(mxv));
        atomicMin(&mn[(size_t)q*COUT + o0 + cst], fmap(mnv));
      }
    }
  }
  // block-end stats reduction + sharded atomics
  __syncthreads();
  T[ps*64 + cst] = sAcc;
  __syncthreads();
  float stot = 0.f;
  if (t < 64) stot = T[t] + T[64+t] + T[128+t] + T[192+t];
  __syncthreads();
  T[ps*64 + cst] = qAcc;
  __syncthreads();
  if (t < 64){
    float qtot = T[t] + T[64+t] + T[128+t] + T[192+t];
    int shard = blockIdx.x & 63;
    atomicAdd(&stat[(size_t)(o0 + t)*64 + shard], stot);
    atomicAdd(&stat[(size_t)COUT*64 + (size_t)(o0 + t)*64 + shard], qtot);
  }
}

// ---------- 8. layer-4 pool finalize ----------
__global__ __launch_bounds__(256) void k_pool4(const unsigned* __restrict__ mx, const unsigned* __restrict__ mn,
    const float* __restrict__ actp, unsigned short* __restrict__ xc){
  int gidx = blockIdx.x*256 + threadIdx.x;
  int q = gidx >> 8, c = gidx & 255;
  float sc = actp[2*c], sh = actp[2*c+1];
  float raw = (sc >= 0.f) ? funmap(mx[gidx]) : funmap(mn[gidx]);
  xc[(size_t)q*512 + 256 + c] = f2h(fmaxf(0.f, sc*raw + sh));
}

// ---------- 9. final: bn5+relu on y5 slabs [8][NPOS][64] f16 -> out [b][512][n] f32 ----------
__global__ void k_out(const unsigned short* __restrict__ y5, const float* __restrict__ actp, float* __restrict__ out){
  __shared__ float tile[32][33];
  int b = blockIdx.z, n0 = blockIdx.x*32, c0 = blockIdx.y*32;
  int lx = threadIdx.x, ly = threadIdx.y;
  int slab = c0 >> 6, cin = (c0 & 63) + lx;
  float sc = actp[2*(c0+lx)], sh = actp[2*(c0+lx)+1];
  const unsigned short* yb = y5 + (size_t)slab*NPOS*64 + (size_t)(b*NN + n0)*64 + cin;
  for (int yy = ly; yy < 32; yy += 8)
    tile[yy][lx] = fmaxf(0.f, sc*h2f(yb[(size_t)yy*64]) + sh);
  __syncthreads();
  for (int yy = ly; yy < 32; yy += 8)
    out[((size_t)(b*512 + c0 + yy))*NN + n0 + lx] = tile[lx][yy];
}

// ---------- launch ----------
extern "C" void kernel_launch(void* const* d_in, const int* in_sizes, int n_in,
                              void* d_out, int out_size, void* d_ws, size_t ws_size,
                              hipStream_t stream){
  const float* pts = (const float*)d_in[0];
  const float* W1 = (const float*)d_in[1];
  const float* W2 = (const float*)d_in[2];
  const float* W3 = (const float*)d_in[3];
  const float* W4 = (const float*)d_in[4];
  const float* W5 = (const float*)d_in[5];
  const float* g1 = (const float*)d_in[6];  const float* b1 = (const float*)d_in[7];
  const float* g2 = (const float*)d_in[8];  const float* b2 = (const float*)d_in[9];
  const float* g3 = (const float*)d_in[10]; const float* b3 = (const float*)d_in[11];
  const float* g4 = (const float*)d_in[12]; const float* b4 = (const float*)d_in[13];
  const float* g5 = (const float*)d_in[14]; const float* b5 = (const float*)d_in[15];

  char* ws = (char*)d_ws;
  // layout (~138 MiB total)
  float*          xt    = (float*)(ws + 0);                      // 256 KB
  unsigned short* idxu  = (unsigned short*)(ws + 262144);        // 640 KB
  float*          stats = (float*)(ws + 917504);                 // 512 KB
  float*          acts  = (float*)(ws + 1441792);                // 8 KB
  // R1 (42MB): y1 -> y3a -> y5
  unsigned short* y1    = (unsigned short*)(ws + 2097152);
  unsigned short* y3a   = (unsigned short*)(ws + 2097152);
  unsigned short* y5    = (unsigned short*)(ws + 2097152);
  // R2 (42MB): y2 -> mx+mn
  unsigned short* y2    = (unsigned short*)(ws + 44040192);
  unsigned*       mx    = (unsigned*)(ws + 44040192);            // 16 MB
  unsigned*       mn    = (unsigned*)(ws + 60817408);            // 16 MB
  // R3 (42MB): y3b
  unsigned short* y3b   = (unsigned short*)(ws + 85983232);
  // xc (16MB f16)
  unsigned short* xc    = (unsigned short*)(ws + 127926272);
  float* out = (float*)d_out;

  float* st1 = stats + 0,  *st2 = stats + 8192, *st3 = stats + 16384, *st4 = stats + 32768, *st5 = stats + 65536;
  float* ac1 = acts + 0,   *ac2 = acts + 128,   *ac3 = acts + 256,    *ac4 = acts + 512,    *ac5 = acts + 1024;
  const size_t y3stride = (size_t)(85983232 - 2097152) / 2;      // elements between y3a and y3b slabs

  hipMemsetAsync(stats, 0, 524288, stream);
  k_demean<<<24, 256, 0, stream>>>(pts, xt);
  k_knn<<<512, 256, 0, stream>>>(xt, idxu);
  k_conv1<<<NEDGE/256, 256, 0, stream>>>(xt, idxu, W1, y1);
  k_stats1<<<256, 256, 0, stream>>>(y1, st1);
  k_fin<<<1, 64, 0, stream>>>(st1, g1, b1, ac1, 64, 1.f/NEDGE);
  k_max64<<<NPOS*32/256, 256, 0, stream>>>(y1, ac1, xc, 0);
  k_mfma<64,64,true,false,false,false><<<dim3(1280,1), 256, 0, stream>>>(
      y1, nullptr, W2, ac1, y2, 0, st2, nullptr, nullptr, 2560);
  k_fin<<<1, 64, 0, stream>>>(st2, g2, b2, ac2, 64, 1.f/NEDGE);
  k_max64<<<NPOS*32/256, 256, 0, stream>>>(y2, ac2, xc, 64);
  k_mfma<64,128,true,false,false,false><<<dim3(640,2), 256, 0, stream>>>(
      y2, nullptr, W3, ac2, y3a, y3stride, st3, nullptr, nullptr, 2560);
  k_fin<<<1, 128, 0, stream>>>(st3, g3, b3, ac3, 128, 1.f/NEDGE);
  k_max64<<<NPOS*32/256, 256, 0, stream>>>(y3a, ac3, xc, 128);
  k_max64<<<NPOS*32/256, 256, 0, stream>>>(y3b, ac3 + 128, xc, 192);
  hipMemsetAsync(mx, 0x00, 16777216, stream);   // mapped -inf
  hipMemsetAsync(mn, 0xFF, 16777216, stream);   // mapped +inf
  k_mfma<128,256,true,true,false,true><<<dim3(320,4), 256, 0, stream>>>(
      y3a, y3b, W4, ac3, nullptr, 0, st4, mx, mn, 2560);
  k_fin<<<1, 256, 0, stream>>>(st4, g4, b4, ac4, 256, 1.f/NEDGE);
  k_pool4<<<NPOS, 256, 0, stream>>>(mx, mn, ac4, xc);
  k_mfma<512,512,false,false,true,false><<<dim3(128,8), 256, 0, stream>>>(
      xc, nullptr, W5, nullptr, y5, (size_t)NPOS*64, st5, nullptr, nullptr, 128);
  k_fin<<<1, 512, 0, stream>>>(st5, g5, b5, ac5, 512, 1.f/NPOS);
  k_out<<<dim3(NN/32, 16, BB), dim3(32, 8), 0, stream>>>(y5, ac5, out);
}